// Round 4
// baseline (2176.303 us; speedup 1.0000x reference)
//
#include <hip/hip_runtime.h>
#include <hip/hip_bf16.h>

typedef __attribute__((ext_vector_type(8))) short bf16x8;
typedef __attribute__((ext_vector_type(4))) float f32x4;
typedef __attribute__((ext_vector_type(4))) unsigned short u16x4;

#define SEQ   4096
#define DIM   1024
#define MTOT  16384

static __device__ __forceinline__ unsigned short f2bf(float f) {
  union { float f; unsigned u; } v; v.f = f;
  unsigned r = v.u + 0x7FFFu + ((v.u >> 16) & 1u);
  return (unsigned short)(r >> 16);
}

static __device__ __forceinline__ bf16x8 pack8(f32x4 a, f32x4 b) {
  bf16x8 v;
  v[0]=(short)f2bf(a[0]); v[1]=(short)f2bf(a[1]);
  v[2]=(short)f2bf(a[2]); v[3]=(short)f2bf(a[3]);
  v[4]=(short)f2bf(b[0]); v[5]=(short)f2bf(b[1]);
  v[6]=(short)f2bf(b[2]); v[7]=(short)f2bf(b[3]);
  return v;
}

// LDS-only barrier: lgkmcnt(0) + s_barrier, leaves vmcnt in flight.
// 0xC07F = vmcnt=63, expcnt=7, lgkmcnt=0 (gfx9 encoding).
static __device__ __forceinline__ void barrier_lds() {
  asm volatile("" ::: "memory");
  __builtin_amdgcn_s_waitcnt(0xC07F);
  __builtin_amdgcn_s_barrier();
  asm volatile("" ::: "memory");
}

// ---------------- fp32 -> bf16 preconvert (optionally scaled) ----------------
__global__ __launch_bounds__(256) void conv_bf16(
    const float* __restrict__ src, unsigned short* __restrict__ dst,
    int n8, float scale)
{
  const int i = blockIdx.x * 256 + threadIdx.x;
  if (i < n8) {
    const f32x4* s = (const f32x4*)(src + (size_t)i * 8);
    f32x4 a = s[0], b = s[1];
#pragma unroll
    for (int r = 0; r < 4; ++r) { a[r] *= scale; b[r] *= scale; }
    *(bf16x8*)(dst + (size_t)i * 8) = pack8(a, b);
  }
}

// ---------------- QKV GEMM, m97-style: 128x128 tile, global_load_lds w16 ----
__global__ __launch_bounds__(256) void qkv_gemm2(
    const unsigned short* __restrict__ xb,
    const unsigned short* __restrict__ Wb,    // Wq|Wk|Wv bf16
    unsigned short* __restrict__ outQ)        // Q | K | Vt contiguous
{
  const int z = blockIdx.z;
  const unsigned short* __restrict__ Wz = Wb + (size_t)z * (DIM * DIM);
  unsigned short* __restrict__ outb = outQ + (size_t)z * ((size_t)MTOT * DIM);

  const int n0 = blockIdx.x * 128;
  const int m0 = blockIdx.y * 128;
  const int tid = threadIdx.x, ln = tid & 63, wv = tid >> 6;
  const int l15 = ln & 15, quad = ln >> 4;
  const int mw = wv >> 1, nw = wv & 1;
  const int lrow = ln >> 3, lcol = (ln & 7) * 8;

  __shared__ unsigned short Al[128 * 64];
  __shared__ unsigned short Bl[128 * 64];

  f32x4 acc[4][4] = {};

  for (int k0 = 0; k0 < DIM; k0 += 64) {
    __syncthreads();
#pragma unroll
    for (int r = 0; r < 4; ++r) {
      const int rr = (wv * 4 + r) * 8 + lrow;
      const unsigned short* ga = xb + (size_t)(m0 + rr) * DIM + k0 + lcol;
      const unsigned short* gb = Wz + (size_t)(n0 + rr) * DIM + k0 + lcol;
      __builtin_amdgcn_global_load_lds(
          (const __attribute__((address_space(1))) void*)ga,
          (__attribute__((address_space(3))) void*)&Al[(wv * 4 + r) * 512], 16, 0, 0);
      __builtin_amdgcn_global_load_lds(
          (const __attribute__((address_space(1))) void*)gb,
          (__attribute__((address_space(3))) void*)&Bl[(wv * 4 + r) * 512], 16, 0, 0);
    }
    __syncthreads();
#pragma unroll
    for (int ks = 0; ks < 2; ++ks) {
      bf16x8 af[4], bfr[4];
#pragma unroll
      for (int i = 0; i < 4; ++i) {
        af[i]  = *(const bf16x8*)&Al[(mw * 64 + i * 16 + l15) * 64 + ks * 32 + quad * 8];
        bfr[i] = *(const bf16x8*)&Bl[(nw * 64 + i * 16 + l15) * 64 + ks * 32 + quad * 8];
      }
#pragma unroll
      for (int mi = 0; mi < 4; ++mi)
#pragma unroll
        for (int ni = 0; ni < 4; ++ni)
          acc[mi][ni] = __builtin_amdgcn_mfma_f32_16x16x32_bf16(af[mi], bfr[ni], acc[mi][ni], 0, 0, 0);
    }
  }

  if (z < 2) {
#pragma unroll
    for (int mi = 0; mi < 4; ++mi)
#pragma unroll
      for (int ni = 0; ni < 4; ++ni) {
        const int m = m0 + mw * 64 + mi * 16 + quad * 4;
        const int e = n0 + nw * 64 + ni * 16 + l15;
        unsigned short* p = outb + (size_t)m * DIM + e;
#pragma unroll
        for (int r = 0; r < 4; ++r) p[(size_t)r * DIM] = f2bf(acc[mi][ni][r]);
      }
  } else {
#pragma unroll
    for (int mi = 0; mi < 4; ++mi)
#pragma unroll
      for (int ni = 0; ni < 4; ++ni) {
        const int m = m0 + mw * 64 + mi * 16 + quad * 4;   // s index
        const int e = n0 + nw * 64 + ni * 16 + l15;
        const int bb = m >> 12, ss = m & 4095;
        u16x4 v4;
#pragma unroll
        for (int r = 0; r < 4; ++r) v4[r] = f2bf(acc[mi][ni][r]);
        *(u16x4*)(outb + ((size_t)bb * DIM + e) * SEQ + ss) = v4;
      }
  }
}

// ---------------- Flash attention v4: INTERLEAVED split-K + K pipeline ----
// 512 blocks x 512 threads. x=bid&7 -> XCD, b=x>>1, o=x&1; j=bid>>3:
// j<32 -> h=0 (even 32-key tiles), j>=32 -> h=1 (odd tiles), t = h?63-j:j,
// P = 2t+o, q0=64P. Iter `it` reads key-tile 2*it+h (j0 = 64*it+32*h) —
// ALL blocks sweep keys in lockstep from j~0 => same-XCD L2 sharing.
// K fragments register-double-buffered: next tile prefetched one full
// iteration ahead; V prefetched across barrier+softmax.
__global__ __launch_bounds__(512) void attn4(
    const unsigned short* __restrict__ Qg,
    const unsigned short* __restrict__ Kg,
    const unsigned short* __restrict__ Vtg,
    float* __restrict__ outp,
    unsigned short* __restrict__ O1,
    float* __restrict__ St)
{
  __shared__ float Sp[8][64][33];
  __shared__ unsigned short Pl[64][40];
  __shared__ float mst[64], lst[64], alf[64];

  const int bid = blockIdx.x;
  const int x = bid & 7, j = bid >> 3;
  const int b = x >> 1, o = x & 1;
  const int h = (j >= 32) ? 1 : 0;
  const int t = h ? (63 - j) : j;
  const int P = 2 * t + o;
  const int q0 = P << 6;
  const int nit = P + 1;

  const int tid  = threadIdx.x;
  const int w    = tid >> 6;
  const int lane = tid & 63;
  const int l15  = lane & 15, quad = lane >> 4;

  if (tid < 64) { mst[tid] = -1e30f; lst[tid] = 0.f; }   // finite sentinel

  bf16x8 qf[4][4];
  const size_t qbase = (size_t)(b * SEQ + q0) * DIM;
#pragma unroll
  for (int mq = 0; mq < 4; ++mq)
#pragma unroll
    for (int ks = 0; ks < 4; ++ks)
      qf[mq][ks] = *(const bf16x8*)(Qg + qbase + (size_t)(mq * 16 + l15) * DIM +
                                    w * 128 + ks * 32 + quad * 8);

  f32x4 oac[8][4] = {};

  const int srow = tid >> 3;
  const int c0   = (tid & 7) * 4;
  const int qg   = q0 + srow;

  // K fragment loader: 8 frags = rows {j0+l15, j0+16+l15} x 4 ks-chunks
  const unsigned short* Kw = Kg + (size_t)b * SEQ * DIM + w * 128 + quad * 8;
  auto load_k = [&](int j0, bf16x8 (&kf)[8]) {
    const unsigned short* kb = Kw + (size_t)(j0 + l15) * DIM;
#pragma unroll
    for (int ks = 0; ks < 4; ++ks) {
      kf[ks]     = *(const bf16x8*)(kb + ks * 32);
      kf[4 + ks] = *(const bf16x8*)(kb + (size_t)16 * DIM + ks * 32);
    }
  };
  const unsigned short* Vw = Vtg + ((size_t)b * DIM + w * 128) * SEQ + quad * 8;

  bf16x8 kA[8], kB[8];
  load_k(32 * h, kA);

  auto step = [&](int it, bf16x8 (&kfc)[8], bf16x8 (&kfn)[8]) {
    const int j0 = 64 * it + 32 * h;

    // ---- V prefetch (this tile), then K prefetch (next tile) ----
    bf16x8 vf[8];
    const unsigned short* vb = Vw + j0;
#pragma unroll
    for (int md = 0; md < 8; ++md)
      vf[md] = *(const bf16x8*)(vb + (size_t)(md * 16 + l15) * SEQ);
    const int jn = (it + 1 < nit) ? j0 + 64 : j0;   // clamp (dummy reload)
    load_k(jn, kfn);

    // ---- partial QK^T over this wave's 128-d slice (Q pre-scaled) ----
    f32x4 sac[4][2] = {};
#pragma unroll
    for (int ks = 0; ks < 4; ++ks) {
#pragma unroll
      for (int mq = 0; mq < 4; ++mq) {
        sac[mq][0] = __builtin_amdgcn_mfma_f32_16x16x32_bf16(qf[mq][ks], kfc[ks],     sac[mq][0], 0, 0, 0);
        sac[mq][1] = __builtin_amdgcn_mfma_f32_16x16x32_bf16(qf[mq][ks], kfc[4 + ks], sac[mq][1], 0, 0, 0);
      }
    }
#pragma unroll
    for (int mq = 0; mq < 4; ++mq)
#pragma unroll
      for (int n = 0; n < 2; ++n)
#pragma unroll
        for (int r = 0; r < 4; ++r)
          Sp[w][mq * 16 + quad * 4 + r][n * 16 + l15] = sac[mq][n][r];

    barrier_lds();   // Sp visible; vf/kfn still in flight

    // ---- online softmax ----
    {
      float s[4];
#pragma unroll
      for (int i = 0; i < 4; ++i) {
        float acc = 0.f;
#pragma unroll
        for (int wv = 0; wv < 8; ++wv) acc += Sp[wv][srow][c0 + i];
        s[i] = (j0 + c0 + i > qg) ? -__builtin_inff() : acc;
      }
      float mx = fmaxf(fmaxf(s[0], s[1]), fmaxf(s[2], s[3]));
#pragma unroll
      for (int off = 1; off < 8; off <<= 1) mx = fmaxf(mx, __shfl_xor(mx, off, 8));
      const float mold = mst[srow];
      const float mnew = fmaxf(mold, mx);
      const float al   = __expf(mold - mnew);
      float pv[4];
#pragma unroll
      for (int i = 0; i < 4; ++i) pv[i] = __expf(s[i] - mnew);
      u16x4 pb;
#pragma unroll
      for (int i = 0; i < 4; ++i) pb[i] = f2bf(pv[i]);
      *(u16x4*)&Pl[srow][c0] = pb;
      float sm = (pv[0] + pv[1]) + (pv[2] + pv[3]);
#pragma unroll
      for (int off = 1; off < 8; off <<= 1) sm += __shfl_xor(sm, off, 8);
      if ((tid & 7) == 0) {
        lst[srow] = lst[srow] * al + sm;
        mst[srow] = mnew;
        alf[srow] = al;
      }
    }
    barrier_lds();   // Pl/alf visible; vf/kfn still in flight

    // ---- rescale O when some alpha != 1 ----
    const float a0 = alf[l15], a1 = alf[16 + l15], a2 = alf[32 + l15], a3 = alf[48 + l15];
    if (__ballot((a0 != 1.f) | (a1 != 1.f) | (a2 != 1.f) | (a3 != 1.f))) {
#pragma unroll
      for (int md = 0; md < 8; ++md)
#pragma unroll
        for (int r = 0; r < 4; ++r) {
          oac[md][0][r] *= a0; oac[md][1][r] *= a1;
          oac[md][2][r] *= a2; oac[md][3][r] *= a3;
        }
    }

    // ---- PV: O^T += V^T * P^T (waits vf only; kfn keeps flying) ----
    bf16x8 pf[4];
#pragma unroll
    for (int nq = 0; nq < 4; ++nq)
      pf[nq] = *(const bf16x8*)&Pl[nq * 16 + l15][quad * 8];
#pragma unroll
    for (int md = 0; md < 8; ++md)
#pragma unroll
      for (int nq = 0; nq < 4; ++nq)
        oac[md][nq] = __builtin_amdgcn_mfma_f32_16x16x32_bf16(vf[md], pf[nq], oac[md][nq], 0, 0, 0);
  };

  int it = 0;
  while (true) {
    step(it, kA, kB);
    if (++it >= nit) break;
    step(it, kB, kA);
    if (++it >= nit) break;
  }

  // ---- epilogue: write partial (unnormalized) + stats ----
  if (tid < 64) {
    const int r = b * SEQ + q0 + tid;
    St[h * MTOT + r]       = mst[tid];
    St[(2 + h) * MTOT + r] = lst[tid];
  }
#pragma unroll
  for (int md = 0; md < 8; ++md)
#pragma unroll
    for (int nq = 0; nq < 4; ++nq) {
      const int qq = q0 + nq * 16 + l15;
      const int d  = w * 128 + md * 16 + quad * 4;
      const size_t ro = (size_t)(b * SEQ + qq) * DIM + d;
      if (h == 0) {
        *(f32x4*)(outp + ro) = oac[md][nq];
      } else {
        u16x4 v4;
#pragma unroll
        for (int r = 0; r < 4; ++r) v4[r] = f2bf(oac[md][nq][r]);
        *(u16x4*)(O1 + ro) = v4;
      }
    }
}

// ---------------- merge the two key-half partials ----------------
__global__ __launch_bounds__(256) void combine(
    float* __restrict__ out, const unsigned short* __restrict__ O1,
    const float* __restrict__ St)
{
  const int r = blockIdx.x;
  const int d = threadIdx.x * 4;
  const float m0 = St[r],            m1 = St[MTOT + r];
  const float l0 = St[2 * MTOT + r], l1 = St[3 * MTOT + r];
  const float M  = fmaxf(m0, m1);
  const float w0 = __expf(m0 - M), w1 = __expf(m1 - M);
  const float inv = 1.0f / (w0 * l0 + w1 * l1);
  f32x4 o0 = *(const f32x4*)(out + (size_t)r * DIM + d);
  u16x4 o1 = *(const u16x4*)(O1 + (size_t)r * DIM + d);
  f32x4 res;
#pragma unroll
  for (int i = 0; i < 4; ++i) {
    union { unsigned u; float f; } c; c.u = ((unsigned)o1[i]) << 16;
    res[i] = (w0 * o0[i] + w1 * c.f) * inv;
  }
  *(f32x4*)(out + (size_t)r * DIM + d) = res;
}

extern "C" void kernel_launch(void* const* d_in, const int* in_sizes, int n_in,
                              void* d_out, int out_size, void* d_ws, size_t ws_size,
                              hipStream_t stream) {
  const float* x  = (const float*)d_in[0];
  const float* Wq = (const float*)d_in[1];
  const float* Wk = (const float*)d_in[2];
  const float* Wv = (const float*)d_in[3];
  float* out = (float*)d_out;

  // ws layout (134.25 MB):
  //   [0,32MB):    xb (bf16 x)        -> later overlaid by O1 (h=1 partial)
  //   [32,38MB):   Wb (bf16 Wq|Wk|Wv) -> later overlaid by St (m/l stats)
  //   [38,70MB):   Q bf16   [70,102MB): K bf16   [102,134MB): Vt bf16
  char* wsb = (char*)d_ws;
  unsigned short* xb = (unsigned short*)wsb;
  unsigned short* Wb = (unsigned short*)(wsb + (32u << 20));
  unsigned short* Qb = (unsigned short*)(wsb + (38u << 20));
  unsigned short* O1 = xb;
  float*          St = (float*)(wsb + (32u << 20));

  conv_bf16<<<8192, 256, 0, stream>>>(x,  xb, 2097152, 1.0f);
  conv_bf16<<<512,  256, 0, stream>>>(Wq, Wb,           131072, 0.03125f); // fold 1/sqrt(D)
  conv_bf16<<<512,  256, 0, stream>>>(Wk, Wb + 1048576, 131072, 1.0f);
  conv_bf16<<<512,  256, 0, stream>>>(Wv, Wb + 2097152, 131072, 1.0f);

  qkv_gemm2<<<dim3(8, 128, 3), 256, 0, stream>>>(xb, Wb, Qb);

  const size_t n = (size_t)MTOT * DIM;
  attn4<<<512, 512, 0, stream>>>(Qb, Qb + n, Qb + 2 * n, out, O1, St);
  combine<<<16384, 256, 0, stream>>>(out, O1, St);
}